// Round 8
// baseline (84.293 us; speedup 1.0000x reference)
//
#include <hip/hip_runtime.h>

// out[co*4+n, ci*4+o, y, x] = sum_{c,ky,kx} k1[co*4+n, ci*4+c, y+ky-7, x+kx-7]
//                                         * k2[co*4+o, ci*4+c, ky, kx]
// MFMA per (co,ci,c,ky):  OUT[y][x] (o=0..3) += sum_u Apad[y+ky][u] * k2[o][ky][u-x]
//   A-frag: lane(y=l&15, kg=l>>4) reads 8 contiguous bf16 (ds_read_b128)
//   B-frag: 8x ds_read_b64 from o-interleaved zero-padded Toeplitz table.
// n-SPLIT ACROSS BLOCKS (R8): grid 128x64, zh=blockIdx.x&1 handles n in {2zh,2zh+1}.
//   acc 64->32 regs -> total ~90-96 regs -> 5 waves/SIMD (vs 4) under bounds(256,5).
//   Apad halves (4 bands); k2 table staged by both pair-blocks (L2-warm dup).
// Apad 2-D shared-pad tiling: 4 vertical bands (stride 22 rows) x 2 horizontal
//   (cols 0/24); only the discarded yl=15 row ever reads a neighbor's data.
// Arena 10640 (Apad) + 15872 (tbl) = 26512 B.

typedef float f32x4 __attribute__((ext_vector_type(4)));
typedef __bf16 bf16x8 __attribute__((ext_vector_type(8)));

#define KS 15
#define SP 225
#define NCH 256
#define RSTRIDE 56                    // shorts per Apad row
#define ROWS 95                       // 22*3 + 29
#define APAD_SHORTS (ROWS * RSTRIDE)  // 5320 shorts = 10640 B
#define TBL_OFF (APAD_SHORTS * 2)     // 10640 B, 16B aligned
#define TBL_UPC 496                   // table units (8B) per input channel c
#define ARENA_B (TBL_OFF + 4 * TBL_UPC * 8)   // 26512 B

__device__ __forceinline__ unsigned short f2bf(float f) {
    unsigned u = __builtin_bit_cast(unsigned, f);
    u += 0x7FFFu + ((u >> 16) & 1u);   // RNE (finite normals)
    return (unsigned short)(u >> 16);
}

__global__ __launch_bounds__(256, 5)
void blade_conv_mfma(const float* __restrict__ k1,
                     const float* __restrict__ k2,
                     float* __restrict__ out) {
    // phase 1: Apad bf16 [95 rows][56 cols] + Toeplitz tbl [4c][496 u64]
    // phase 2: slabs f32 [4 wid][4 o][16 x][20 y] = 20480 B (overlaid)
    __shared__ __align__(16) unsigned char arena[ARENA_B];
    unsigned short*     Apad  = (unsigned short*)arena;
    unsigned long long* tbl   = (unsigned long long*)(arena + TBL_OFF);
    float*              slabs = (float*)arena;

    const int tid  = threadIdx.x;
    const int lane = tid & 63;
    const int wid  = tid >> 6;            // wave id == input channel c
    const int zh = blockIdx.x & 1;        // n-half: n in {2zh, 2zh+1}
    const int co = blockIdx.x >> 1, ci = blockIdx.y;

    // ---- zero whole arena ----
    f32x4 z = {0.f, 0.f, 0.f, 0.f};
    for (int i = tid; i < ARENA_B / 16; i += 256) ((f32x4*)arena)[i] = z;
    __syncthreads();

    // ---- stage k1 half-slice (8 planes) -> Apad ----
    for (int idx = tid; idx < 8 * SP; idx += 256) {
        int nc = idx / SP, rem = idx % SP;
        int y = rem / KS, x = rem % KS;
        int np = nc >> 2, c = nc & 3;           // np in {0,1}
        int n = zh * 2 + np;
        float v = k1[((size_t)((co * 4 + n) * NCH + ci * 4 + c)) * SP + rem];
        int band = np * 2 + (c >> 1), side = c & 1;
        Apad[(band * 22 + 7 + y) * RSTRIDE + side * 24 + 7 + x] = f2bf(v);
    }

    // ---- stage k2 -> o-interleaved Toeplitz table ----
    for (int idx = tid; idx < 4 * SP; idx += 256) {
        int c = idx / SP, rem = idx % SP;
        int ky = rem / KS, kx = rem % KS;
        size_t base = ((size_t)(co * 4) * NCH + ci * 4 + c) * SP + rem;  // o=0
        float v0 = k2[base];
        float v1 = k2[base + (size_t)NCH * SP];
        float v2 = k2[base + 2 * (size_t)NCH * SP];
        float v3 = k2[base + 3 * (size_t)NCH * SP];
        unsigned lo = (unsigned)f2bf(v0) | ((unsigned)f2bf(v1) << 16);
        unsigned hi = (unsigned)f2bf(v2) | ((unsigned)f2bf(v3) << 16);
        tbl[c * TBL_UPC + 32 * ky + kx + 15] =
            (unsigned long long)lo | ((unsigned long long)hi << 32);
    }
    __syncthreads();

    // ---- K loop: 15 ky chunks, K=32 (u) each ----
    f32x4 acc[2][4];
    #pragma unroll
    for (int np = 0; np < 2; ++np)
        #pragma unroll
        for (int o = 0; o < 4; ++o)
            acc[np][o] = z;

    const int yl    = lane & 15;       // output y (M); also consuming x for B
    const int kg    = lane >> 4;       // k-group
    const int side_w = wid & 1, whalf = wid >> 1;
    const int acol  = side_w * 24 + (kg << 3);
    const unsigned long long* tbase =
        &tbl[wid * TBL_UPC + (kg << 3) - yl + 15];

    #pragma unroll
    for (int ky = 0; ky < 15; ++ky) {
        bf16x8 af[2];
        #pragma unroll
        for (int np = 0; np < 2; ++np) {
            int band = np * 2 + whalf;
            af[np] = *(const bf16x8*)&Apad[(band * 22 + yl + ky) * RSTRIDE + acol];
        }
        unsigned long long q[8];
        #pragma unroll
        for (int j = 0; j < 8; ++j) q[j] = tbase[32 * ky + j];

        union { bf16x8 v; unsigned u[4]; } bo0, bo1, bo2, bo3;
        #pragma unroll
        for (int t = 0; t < 4; ++t) {
            unsigned a0 = (unsigned)q[2 * t],         a1 = (unsigned)q[2 * t + 1];
            unsigned b0 = (unsigned)(q[2 * t] >> 32), b1 = (unsigned)(q[2 * t + 1] >> 32);
            bo0.u[t] = __builtin_amdgcn_perm(a1, a0, 0x05040100u);
            bo1.u[t] = __builtin_amdgcn_perm(a1, a0, 0x07060302u);
            bo2.u[t] = __builtin_amdgcn_perm(b1, b0, 0x05040100u);
            bo3.u[t] = __builtin_amdgcn_perm(b1, b0, 0x07060302u);
        }
        #pragma unroll
        for (int np = 0; np < 2; ++np) {
            acc[np][0] = __builtin_amdgcn_mfma_f32_16x16x32_bf16(af[np], bo0.v, acc[np][0], 0, 0, 0);
            acc[np][1] = __builtin_amdgcn_mfma_f32_16x16x32_bf16(af[np], bo1.v, acc[np][1], 0, 0, 0);
            acc[np][2] = __builtin_amdgcn_mfma_f32_16x16x32_bf16(af[np], bo2.v, acc[np][2], 0, 0, 0);
            acc[np][3] = __builtin_amdgcn_mfma_f32_16x16x32_bf16(af[np], bo3.v, acc[np][3], 0, 0, 0);
        }
    }

    // ---- cross-wave (c) reduction: 2 rounds, 4 (o) tiles each (np = round) ----
    const int xl = lane & 15;
    #pragma unroll
    for (int g = 0; g < 2; ++g) {
        __syncthreads();   // g=0: Apad/tbl reads done; g=1: prev readout done
        {
            float* slab = slabs + wid * 1280;   // [4 o][16 x][20 y]
            #pragma unroll
            for (int o = 0; o < 4; ++o)
                *(f32x4*)&slab[(o * 16 + xl) * 20 + (kg << 2)] = acc[g][o];
        }
        __syncthreads();
        for (int idx = tid; idx < 4 * SP; idx += 256) {
            int o = idx / SP, rem = idx % SP;
            int yy = rem / KS, xx = rem % KS;
            int soff = (o * 16 + xx) * 20 + yy;
            float s = slabs[soff] + slabs[1280 + soff]
                    + slabs[2560 + soff] + slabs[3840 + soff];
            int n = zh * 2 + g;
            out[((size_t)((co * 4 + n) * NCH + ci * 4 + o)) * SP + rem] = s;
        }
    }
}

extern "C" void kernel_launch(void* const* d_in, const int* in_sizes, int n_in,
                              void* d_out, int out_size, void* d_ws, size_t ws_size,
                              hipStream_t stream) {
    (void)in_sizes; (void)n_in; (void)d_ws; (void)ws_size; (void)out_size;
    const float* k1 = (const float*)d_in[0];
    const float* k2 = (const float*)d_in[1];
    float* out = (float*)d_out;

    dim3 grid(128, 64, 1);
    dim3 block(256, 1, 1);
    hipLaunchKernelGGL(blade_conv_mfma, grid, block, 0, stream, k1, k2, out);
}

// Round 9
// 77.576 us; speedup vs baseline: 1.0866x; 1.0866x over previous
//
#include <hip/hip_runtime.h>

// out[co*4+n, ci*4+o, y, x] = sum_{c,ky,kx} k1[co*4+n, ci*4+c, y+ky-7, x+kx-7]
//                                         * k2[co*4+o, ci*4+c, ky, kx]
// MFMA per (co,ci,c,ky):  OUT[y][x] (o=0..3) += sum_u Apad[y+ky][u] * k2[o][ky][u-x]
//   A-frag: lane(y=l&15, kg=l>>4) reads 8 contiguous bf16 (ds_read_b128)
//   B-frag: 8x ds_read_b64 from o-interleaved zero-padded Toeplitz table.
// R9: 8-WAVE BLOCKS (512 thr), wave = (c, np): c = wid&3 input channel,
//   np = wid>>2 handles n in {2np, 2np+1} with acc[2][4] = 32 regs.
//   Everything staged ONCE per (co,ci) (R8's pair-duplication removed).
//   Residency: regs ~72 -> 7 w/SIMD; LDS 36368 -> 4 blocks; => 3 blocks/CU (75%).
// Apad 2-D shared-pad tiling: 8 vertical bands (stride 22 rows) x 2 horizontal
//   (cols 0/24); only the discarded yl=15 output row ever reads neighbor data.
// Toeplitz tbl rows stride 32 units share zeros (window 46 ends < next row's
//   real data at local 15+32).

typedef float f32x4 __attribute__((ext_vector_type(4)));
typedef __bf16 bf16x8 __attribute__((ext_vector_type(8)));

#define KS 15
#define SP 225
#define NCH 256
#define RSTRIDE 56                    // shorts per Apad row
#define ROWS 183                      // 22*7 + 29
#define APAD_SHORTS (ROWS * RSTRIDE)  // 10248 shorts = 20496 B
#define TBL_OFF (APAD_SHORTS * 2)     // 20496 B, 16B aligned
#define TBL_UPC 496                   // table units (8B) per input channel c
#define ARENA_B (TBL_OFF + 4 * TBL_UPC * 8)   // 36368 B

__device__ __forceinline__ unsigned short f2bf(float f) {
    unsigned u = __builtin_bit_cast(unsigned, f);
    u += 0x7FFFu + ((u >> 16) & 1u);   // RNE (finite normals)
    return (unsigned short)(u >> 16);
}

__global__ __launch_bounds__(512, 6)
void blade_conv_mfma(const float* __restrict__ k1,
                     const float* __restrict__ k2,
                     float* __restrict__ out) {
    // phase 1: Apad bf16 [183 rows][56 cols] + Toeplitz tbl [4c][496 u64]
    // phase 2: slabs f32 [8 wid][2 oi][16 x][20 y] = 20480 B (overlays Apad only)
    __shared__ __align__(16) unsigned char arena[ARENA_B];
    unsigned short*     Apad  = (unsigned short*)arena;
    unsigned long long* tbl   = (unsigned long long*)(arena + TBL_OFF);
    float*              slabs = (float*)arena;

    const int tid  = threadIdx.x;
    const int lane = tid & 63;
    const int wid  = tid >> 6;            // 8 waves
    const int c_w  = wid & 3;             // input channel c
    const int np   = wid >> 2;            // n-half: n in {2np, 2np+1}
    const int co = blockIdx.x, ci = blockIdx.y;

    // ---- zero whole arena (36368/16 = 2273 f32x4) ----
    f32x4 z = {0.f, 0.f, 0.f, 0.f};
    for (int i = tid; i < ARENA_B / 16; i += 512) ((f32x4*)arena)[i] = z;
    __syncthreads();

    // ---- staging: thread (lo < 225, half) owns one (y,x) cell ----
    {
        const int lo = tid & 255, half = tid >> 8;
        if (lo < 225) {
            const int y = lo / 15, x = lo - y * 15;
            // k1: planes 8*half .. 8*half+7  (n = 2*half + j>>2, c = j&3)
            #pragma unroll
            for (int j = 0; j < 8; ++j) {
                int n = 2 * half + (j >> 2), cc = j & 3;
                float v = k1[((size_t)((co * 4 + n) * NCH + ci * 4 + cc)) * SP + lo];
                int band = n * 2 + (cc >> 1), side = cc & 1;
                Apad[(band * 22 + 7 + y) * RSTRIDE + side * 24 + 7 + x] = f2bf(v);
            }
            // k2: channels c = 2*half, 2*half+1  (ky=y, kx=x)
            #pragma unroll
            for (int jj = 0; jj < 2; ++jj) {
                int cc = 2 * half + jj;
                size_t base = ((size_t)(co * 4) * NCH + ci * 4 + cc) * SP + lo;  // o=0
                float v0 = k2[base];
                float v1 = k2[base + (size_t)NCH * SP];
                float v2 = k2[base + 2 * (size_t)NCH * SP];
                float v3 = k2[base + 3 * (size_t)NCH * SP];
                unsigned lw = (unsigned)f2bf(v0) | ((unsigned)f2bf(v1) << 16);
                unsigned hw = (unsigned)f2bf(v2) | ((unsigned)f2bf(v3) << 16);
                tbl[cc * TBL_UPC + 32 * y + x + 15] =
                    (unsigned long long)lw | ((unsigned long long)hw << 32);
            }
        }
    }
    __syncthreads();

    // ---- K loop: 15 ky chunks, K=32 (u) each ----
    f32x4 acc[2][4];
    #pragma unroll
    for (int g = 0; g < 2; ++g)
        #pragma unroll
        for (int o = 0; o < 4; ++o)
            acc[g][o] = z;

    const int yl    = lane & 15;       // output y (M); also consuming x for B
    const int kg    = lane >> 4;       // k-group
    const int side_w = c_w & 1, whalf = c_w >> 1;
    const int acol  = side_w * 24 + (kg << 3);
    const unsigned long long* tbase =
        &tbl[c_w * TBL_UPC + (kg << 3) - yl + 15];

    #pragma unroll
    for (int ky = 0; ky < 15; ++ky) {
        bf16x8 af[2];
        #pragma unroll
        for (int g = 0; g < 2; ++g) {
            int band = (2 * np + g) * 2 + whalf;
            af[g] = *(const bf16x8*)&Apad[(band * 22 + yl + ky) * RSTRIDE + acol];
        }
        unsigned long long q[8];
        #pragma unroll
        for (int j = 0; j < 8; ++j) q[j] = tbase[32 * ky + j];

        union { bf16x8 v; unsigned u[4]; } bo0, bo1, bo2, bo3;
        #pragma unroll
        for (int t = 0; t < 4; ++t) {
            unsigned a0 = (unsigned)q[2 * t],         a1 = (unsigned)q[2 * t + 1];
            unsigned b0 = (unsigned)(q[2 * t] >> 32), b1 = (unsigned)(q[2 * t + 1] >> 32);
            bo0.u[t] = __builtin_amdgcn_perm(a1, a0, 0x05040100u);
            bo1.u[t] = __builtin_amdgcn_perm(a1, a0, 0x07060302u);
            bo2.u[t] = __builtin_amdgcn_perm(b1, b0, 0x05040100u);
            bo3.u[t] = __builtin_amdgcn_perm(b1, b0, 0x07060302u);
        }
        #pragma unroll
        for (int g = 0; g < 2; ++g) {
            acc[g][0] = __builtin_amdgcn_mfma_f32_16x16x32_bf16(af[g], bo0.v, acc[g][0], 0, 0, 0);
            acc[g][1] = __builtin_amdgcn_mfma_f32_16x16x32_bf16(af[g], bo1.v, acc[g][1], 0, 0, 0);
            acc[g][2] = __builtin_amdgcn_mfma_f32_16x16x32_bf16(af[g], bo2.v, acc[g][2], 0, 0, 0);
            acc[g][3] = __builtin_amdgcn_mfma_f32_16x16x32_bf16(af[g], bo3.v, acc[g][3], 0, 0, 0);
        }
    }

    // ---- cross-wave (c) reduction: 4 rounds (g = r>>1, o-pair = r&1) ----
    const int xl = lane & 15;
    #pragma unroll
    for (int r = 0; r < 4; ++r) {
        const int g = r >> 1, op = r & 1;
        __syncthreads();   // r=0: Apad/tbl reads done; r>0: prev readout done
        {
            float* slab = slabs + wid * 640;   // [2 oi][16 x][20 y]
            #pragma unroll
            for (int oi = 0; oi < 2; ++oi)
                *(f32x4*)&slab[(oi * 16 + xl) * 20 + (kg << 2)] = acc[g][2 * op + oi];
        }
        __syncthreads();
        for (int idx = tid; idx < 900; idx += 512) {
            int q4 = idx / 225;                 // 0..3 = (np_g, oi)
            int rem = idx - q4 * 225;
            int np_g = q4 >> 1, oi = q4 & 1;
            int yy = rem / 15, xx = rem - yy * 15;
            int soff = (oi * 16 + xx) * 20 + yy;
            const float* sb = slabs + np_g * 2560;
            float s = sb[soff] + sb[640 + soff] + sb[1280 + soff] + sb[1920 + soff];
            int n = 2 * np_g + g, o = 2 * op + oi;
            out[((size_t)((co * 4 + n) * NCH + ci * 4 + o)) * SP + rem] = s;
        }
    }
}

extern "C" void kernel_launch(void* const* d_in, const int* in_sizes, int n_in,
                              void* d_out, int out_size, void* d_ws, size_t ws_size,
                              hipStream_t stream) {
    (void)in_sizes; (void)n_in; (void)d_ws; (void)ws_size; (void)out_size;
    const float* k1 = (const float*)d_in[0];
    const float* k2 = (const float*)d_in[1];
    float* out = (float*)d_out;

    dim3 grid(64, 64, 1);
    dim3 block(512, 1, 1);
    hipLaunchKernelGGL(blade_conv_mfma, grid, block, 0, stream, k1, k2, out);
}